// Round 9
// baseline (312.120 us; speedup 1.0000x reference)
//
#include <hip/hip_runtime.h>

#define Bsz 4
#define Tn 2048
#define Cn 1024
#define Hn 16
#define Dn 64
#define Mn (Bsz * Tn)      // 8192
#define NQKV (3 * Cn)      // 3072
#define BH (Bsz * Hn)      // 64

typedef short bf16x8_t __attribute__((ext_vector_type(8)));
typedef float f32x4 __attribute__((ext_vector_type(4)));

static __device__ __forceinline__ float exp2_fast(float x) {
    return __builtin_amdgcn_exp2f(x);  // v_exp_f32 (base-2)
}

static __device__ __forceinline__ unsigned short f2bf(float f) {
    union { float f; unsigned int u; } v; v.f = f;
    unsigned int r = v.u + 0x7FFFu + ((v.u >> 16) & 1u);  // RNE
    return (unsigned short)(r >> 16);
}

static __device__ __forceinline__ unsigned int fbits(float f) {
    union { float f; unsigned int u; } v; v.f = f; return v.u;
}

static __device__ __forceinline__ bf16x8_t ld_frag(const unsigned short* p) {
    bf16x8_t r;
    *reinterpret_cast<float4*>(&r) = *reinterpret_cast<const float4*>(p);
    return r;
}

// async global->LDS, 16B per lane; LDS dest = wave-uniform base + lane*16
#define ASYNC_COPY16(gp, lp)                                                         \
    __builtin_amdgcn_global_load_lds((__attribute__((address_space(1))) void*)(gp),  \
                                     (__attribute__((address_space(3))) void*)(lp),  \
                                     16, 0, 0)

// ---------------- cast f32 -> bf16 (vectorized) ----------------
__global__ void cast_f32_bf16(const float* __restrict__ src,
                              unsigned short* __restrict__ dst, int n4) {
    int i = blockIdx.x * blockDim.x + threadIdx.x;
    if (i < n4) {
        float4 v = reinterpret_cast<const float4*>(src)[i];
        ushort4 o;
        o.x = f2bf(v.x); o.y = f2bf(v.y); o.z = f2bf(v.z); o.w = f2bf(v.w);
        reinterpret_cast<ushort4*>(dst)[i] = o;
    }
}

// ---------------- cast + transpose: dst[c*R + r] = bf16(src[r*Cc + c]) ----------------
__global__ void transpose_cast(const float* __restrict__ src,
                               unsigned short* __restrict__ dst, int R, int Cc) {
    __shared__ float tile[32][33];
    int c0 = blockIdx.x * 32, r0 = blockIdx.y * 32;
    int tx = threadIdx.x & 31, ty = threadIdx.x >> 5;  // 256 threads: ty 0..7
#pragma unroll
    for (int i = 0; i < 4; i++)
        tile[ty + i * 8][tx] = src[(long)(r0 + ty + i * 8) * Cc + c0 + tx];
    __syncthreads();
#pragma unroll
    for (int i = 0; i < 4; i++)
        dst[(long)(c0 + ty + i * 8) * R + r0 + tx] = f2bf(tile[tx][ty + i * 8]);
}

// ---------------- GEMM 128x128 (R4-proven structure, BK=32) + 4-chunk XOR swizzle ----
// LDS row = 32 elems (4 chunks of 8). Slot c of row r holds global chunk c^((r>>1)&3).
// Reader fetches slot quad^((l15>>1)&3) -> quarter-wave spreads over all 8 dword-bases
// -> 2-way bank aliasing only (free, m136), vs 8-way unswizzled.
// MODE 0: write fp32 to outF.  MODE 1: qkv scatter -> Qb (pre-scaled 0.125*log2e) / Kb, Vt.
template <int MODE>
__global__ __launch_bounds__(256) void gemm128(const unsigned short* __restrict__ A,
                                               const unsigned short* __restrict__ Bt,
                                               const float* __restrict__ bias,
                                               float* __restrict__ outF,
                                               unsigned short* __restrict__ Qb,
                                               unsigned short* __restrict__ Kb,
                                               unsigned short* __restrict__ Vt,
                                               int M, int N, int Kd) {
    __shared__ __align__(16) unsigned short As[128 * 32];
    __shared__ __align__(16) unsigned short Bs[128 * 32];
    int n0 = blockIdx.x * 128, m0 = blockIdx.y * 128;
    int tid = threadIdx.x;
    int lane = tid & 63, w = tid >> 6;
    int wm = w >> 1, wn = w & 1;
    int quad = lane >> 4, l15 = lane & 15;
    int r16 = lane >> 2, c4 = lane & 3;            // staging: 16 rows x 4 chunks per instr
    int gc = (c4 ^ ((r16 >> 1) & 3)) * 8;          // swizzled global chunk offset (elems)

    // wave w stages rows [w*32, w*32+32) of A and of B, 2 instrs each (16 rows/instr)
    const unsigned short* AgBase = A + (long)(m0 + w * 32 + r16) * Kd + gc;
    const unsigned short* BgBase = Bt + (long)(n0 + w * 32 + r16) * Kd + gc;
    unsigned short* ldsA = As + (w * 32) * 32;
    unsigned short* ldsB = Bs + (w * 32) * 32;

    f32x4 acc[4][4] = {};
    int sw = (l15 >> 1) & 3;  // reader swizzle key ((row>>1)&3; fragment-row base == 0 mod 16)

    for (int kb = 0; kb < Kd; kb += 32) {
        ASYNC_COPY16(AgBase + kb, ldsA);
        ASYNC_COPY16(AgBase + 16 * Kd + kb, ldsA + 512);
        ASYNC_COPY16(BgBase + kb, ldsB);
        ASYNC_COPY16(BgBase + 16 * Kd + kb, ldsB + 512);
        __syncthreads();  // drains vmcnt -> staged tile visible
        bf16x8_t af[4], bfr[4];
#pragma unroll
        for (int i = 0; i < 4; i++)
            af[i] = ld_frag(&As[(wm * 64 + i * 16 + l15) * 32 + ((quad ^ sw) * 8)]);
#pragma unroll
        for (int j = 0; j < 4; j++)
            bfr[j] = ld_frag(&Bs[(wn * 64 + j * 16 + l15) * 32 + ((quad ^ sw) * 8)]);
#pragma unroll
        for (int i = 0; i < 4; i++)
#pragma unroll
            for (int j = 0; j < 4; j++)
                acc[i][j] = __builtin_amdgcn_mfma_f32_16x16x32_bf16(af[i], bfr[j], acc[i][j], 0, 0, 0);
        __syncthreads();  // all reads done before next stage overwrites
    }

#pragma unroll
    for (int i = 0; i < 4; i++)
#pragma unroll
        for (int j = 0; j < 4; j++) {
            int col = n0 + wn * 64 + j * 16 + l15;
            float bval = bias[col];
#pragma unroll
            for (int rr = 0; rr < 4; rr++) {
                int row = m0 + wm * 64 + i * 16 + quad * 4 + rr;
                float val = acc[i][j][rr] + bval;
                if (MODE == 0) {
                    outF[(long)row * N + col] = val;
                } else {
                    int seg = col >> 10, within = col & 1023;
                    int h = within >> 6, d = within & 63;
                    int b = row >> 11, t = row & 2047;
                    int bh = b * Hn + h;
                    if (seg == 0) {
                        // fold 1/sqrt(D) AND log2(e) so softmax uses exp2 directly
                        Qb[((long)bh * Tn + t) * Dn + d] = f2bf(val * 0.18033688f);
                    } else if (seg == 1) {
                        Kb[((long)bh * Tn + t) * Dn + d] = f2bf(val);
                    } else {
                        Vt[((long)bh * Dn + d) * Tn + t] = f2bf(val);
                    }
                }
            }
        }
}

// ---------------- Flash attention v3 (unchanged from R4 run) ----------------
// Block = 4 waves, covers a 128-row q-stripe (32 q rows/wave as 2 halves).
// Stripes paired {qi, 15-qi} -> uniform 34 key-tiles/block. K/V tiles staged
// cooperatively into padded LDS with register-prefetch pipeline (1 tile ahead).
__global__ __launch_bounds__(256) void attn_kernel(const unsigned short* __restrict__ Qb,
                                                   const unsigned short* __restrict__ Kb,
                                                   const unsigned short* __restrict__ Vt,
                                                   unsigned short* __restrict__ Yb) {
    __shared__ __align__(16) unsigned short Ks[64 * 72];
    __shared__ __align__(16) unsigned short Vs[64 * 72];
    __shared__ __align__(16) unsigned short Plds[4][2][16 * 72];
    int tid = threadIdx.x, w = tid >> 6, lane = tid & 63;
    int quad = lane >> 4, l15 = lane & 15;

    // XCD swizzle: all 8 stripe-blocks of one bh land on the same XCD (id%8 heuristic)
    int flat = blockIdx.y * 8 + blockIdx.x;
    int xcd = flat & 7, slot = flat >> 3;
    int bh = xcd * 8 + (slot >> 3);
    int qx = slot & 7;
    int b = bh >> 4, h = bh & 15;

    const unsigned short* Qh = Qb + (long)bh * Tn * Dn;
    const unsigned short* Kh = Kb + (long)bh * Tn * Dn;
    const unsigned short* Vh = Vt + (long)bh * Dn * Tn;

    int sr = tid >> 3;          // staging row 0..31
    int sc = (tid & 7) * 8;     // staging elem offset

#pragma unroll 1
    for (int s = 0; s < 2; s++) {
        int qi = s ? (15 - qx) : qx;
        int q0b = qi * 128;
        int nt = 2 * qi + 2;

        bf16x8_t qf[2][2];
#pragma unroll
        for (int h2 = 0; h2 < 2; h2++) {
            int qrow = q0b + h2 * 64 + w * 16 + l15;
            qf[h2][0] = ld_frag(&Qh[qrow * Dn + quad * 8]);
            qf[h2][1] = ld_frag(&Qh[qrow * Dn + 32 + quad * 8]);
        }

        float m_run[2] = {-1e30f, -1e30f}, l_run[2] = {0.f, 0.f};
        f32x4 Of[2][4] = {};

        // prefetch tile 0 into registers
        float4 kr0 = *reinterpret_cast<const float4*>(&Kh[sr * Dn + sc]);
        float4 kr1 = *reinterpret_cast<const float4*>(&Kh[(32 + sr) * Dn + sc]);
        float4 vr0 = *reinterpret_cast<const float4*>(&Vh[sr * Tn + sc]);
        float4 vr1 = *reinterpret_cast<const float4*>(&Vh[(32 + sr) * Tn + sc]);

#pragma unroll 1
        for (int t = 0; t < nt; t++) {
            int kt0 = t * 64;
            __syncthreads();  // everyone done reading previous LDS tile
            *reinterpret_cast<float4*>(&Ks[sr * 72 + sc]) = kr0;
            *reinterpret_cast<float4*>(&Ks[(32 + sr) * 72 + sc]) = kr1;
            *reinterpret_cast<float4*>(&Vs[sr * 72 + sc]) = vr0;
            *reinterpret_cast<float4*>(&Vs[(32 + sr) * 72 + sc]) = vr1;
            if (t + 1 < nt) {  // issue next tile's loads; latency hides behind compute(t)
                int kn = kt0 + 64;
                kr0 = *reinterpret_cast<const float4*>(&Kh[(kn + sr) * Dn + sc]);
                kr1 = *reinterpret_cast<const float4*>(&Kh[(kn + 32 + sr) * Dn + sc]);
                vr0 = *reinterpret_cast<const float4*>(&Vh[sr * Tn + kn + sc]);
                vr1 = *reinterpret_cast<const float4*>(&Vh[(32 + sr) * Tn + kn + sc]);
            }
            __syncthreads();  // staged tile visible

            bool act0 = (kt0 <= q0b);  // half 0 active? (block-uniform)

            // QK^T for both halves, sharing K fragments
            f32x4 st[2][4];
#pragma unroll
            for (int ti = 0; ti < 4; ti++) {
                bf16x8_t ka0 = ld_frag(&Ks[(ti * 16 + l15) * 72 + quad * 8]);
                bf16x8_t ka1 = ld_frag(&Ks[(ti * 16 + l15) * 72 + 32 + quad * 8]);
                if (act0) {
                    f32x4 z = {};
                    z = __builtin_amdgcn_mfma_f32_16x16x32_bf16(ka0, qf[0][0], z, 0, 0, 0);
                    st[0][ti] = __builtin_amdgcn_mfma_f32_16x16x32_bf16(ka1, qf[0][1], z, 0, 0, 0);
                }
                f32x4 z1 = {};
                z1 = __builtin_amdgcn_mfma_f32_16x16x32_bf16(ka0, qf[1][0], z1, 0, 0, 0);
                st[1][ti] = __builtin_amdgcn_mfma_f32_16x16x32_bf16(ka1, qf[1][1], z1, 0, 0, 0);
            }

            // softmax + P-pack per half
            bf16x8_t pa[2][2];
#pragma unroll
            for (int h2 = 0; h2 < 2; h2++) {
                int qbase = q0b + h2 * 64;
                if (h2 == 0 && !act0) continue;
                if (kt0 == qbase) {  // diagonal tile: causal mask
                    int q_glob = qbase + w * 16 + l15;
#pragma unroll
                    for (int ti = 0; ti < 4; ti++)
#pragma unroll
                        for (int rr = 0; rr < 4; rr++)
                            if (kt0 + ti * 16 + quad * 4 + rr > q_glob) st[h2][ti][rr] = -1e30f;
                }
                float lmax = st[h2][0][0];
#pragma unroll
                for (int ti = 0; ti < 4; ti++)
#pragma unroll
                    for (int rr = 0; rr < 4; rr++) lmax = fmaxf(lmax, st[h2][ti][rr]);
                lmax = fmaxf(lmax, __shfl_xor(lmax, 16));
                lmax = fmaxf(lmax, __shfl_xor(lmax, 32));
                float m_new = fmaxf(m_run[h2], lmax);
                float alpha = exp2_fast(m_run[h2] - m_new);
                float lsum = 0.f;
#pragma unroll
                for (int ti = 0; ti < 4; ti++)
#pragma unroll
                    for (int rr = 0; rr < 4; rr++) {
                        float e = exp2_fast(st[h2][ti][rr] - m_new);
                        st[h2][ti][rr] = e;
                        lsum += e;
                    }
                lsum += __shfl_xor(lsum, 16);
                lsum += __shfl_xor(lsum, 32);
                l_run[h2] = l_run[h2] * alpha + lsum;
                m_run[h2] = m_new;
#pragma unroll
                for (int rr = 0; rr < 4; rr++) {
                    float a_rr = __shfl(alpha, quad * 4 + rr);
#pragma unroll
                    for (int dt = 0; dt < 4; dt++) Of[h2][dt][rr] *= a_rr;
                }
                unsigned short* Pw = &Plds[w][h2][0];
#pragma unroll
                for (int ti = 0; ti < 4; ti++) {
                    unsigned u0 = fbits(st[h2][ti][0]) + 0x8000u;
                    unsigned u1 = fbits(st[h2][ti][1]) + 0x8000u;
                    unsigned u2 = fbits(st[h2][ti][2]) + 0x8000u;
                    unsigned u3 = fbits(st[h2][ti][3]) + 0x8000u;
                    uint2 pk;
                    pk.x = __builtin_amdgcn_perm(u1, u0, 0x07060302);
                    pk.y = __builtin_amdgcn_perm(u3, u2, 0x07060302);
                    *reinterpret_cast<uint2*>(&Pw[l15 * 72 + ti * 16 + quad * 4]) = pk;
                }
#pragma unroll
                for (int kc = 0; kc < 2; kc++)
                    pa[h2][kc] = ld_frag(&Pw[l15 * 72 + kc * 32 + quad * 8]);
            }

            // PV for both halves, sharing V fragments
#pragma unroll
            for (int kc = 0; kc < 2; kc++)
#pragma unroll
                for (int dt = 0; dt < 4; dt++) {
                    bf16x8_t vb = ld_frag(&Vs[(dt * 16 + l15) * 72 + kc * 32 + quad * 8]);
                    if (act0)
                        Of[0][dt] = __builtin_amdgcn_mfma_f32_16x16x32_bf16(pa[0][kc], vb, Of[0][dt], 0, 0, 0);
                    Of[1][dt] = __builtin_amdgcn_mfma_f32_16x16x32_bf16(pa[1][kc], vb, Of[1][dt], 0, 0, 0);
                }
        }

#pragma unroll
        for (int h2 = 0; h2 < 2; h2++) {
            int qw = q0b + h2 * 64 + w * 16;
#pragma unroll
            for (int rr = 0; rr < 4; rr++) {
                float linv = 1.f / __shfl(l_run[h2], quad * 4 + rr);
                int t = qw + quad * 4 + rr;
                long rowbase = ((long)(b * Tn + t)) * Cn + h * Dn;
#pragma unroll
                for (int dt = 0; dt < 4; dt++)
                    Yb[rowbase + dt * 16 + l15] = f2bf(Of[h2][dt][rr] * linv);
            }
        }
    }
}

extern "C" void kernel_launch(void* const* d_in, const int* in_sizes, int n_in,
                              void* d_out, int out_size, void* d_ws, size_t ws_size,
                              hipStream_t stream) {
    const float* x      = (const float*)d_in[0];
    const float* W_attn = (const float*)d_in[1];
    const float* b_attn = (const float*)d_in[2];
    const float* W_proj = (const float*)d_in[3];
    const float* b_proj = (const float*)d_in[4];
    float* out = (float*)d_out;

    unsigned short* xb      = (unsigned short*)d_ws;                 // [8192,1024]
    unsigned short* Wqkv_t  = xb + (size_t)Mn * Cn;                  // [3072,1024]
    unsigned short* Wproj_t = Wqkv_t + (size_t)NQKV * Cn;            // [1024,1024]
    unsigned short* Qb      = Wproj_t + (size_t)Cn * Cn;             // [64,2048,64]
    unsigned short* Kb      = Qb + (size_t)BH * Tn * Dn;
    unsigned short* Vt      = Kb + (size_t)BH * Tn * Dn;             // [64,64,2048]
    unsigned short* Yb      = Vt + (size_t)BH * Tn * Dn;             // [8192,1024]

    cast_f32_bf16<<<(Mn * Cn / 4 + 255) / 256, 256, 0, stream>>>(x, xb, Mn * Cn / 4);
    transpose_cast<<<dim3(NQKV / 32, Cn / 32), 256, 0, stream>>>(W_attn, Wqkv_t, Cn, NQKV);
    transpose_cast<<<dim3(Cn / 32, Cn / 32), 256, 0, stream>>>(W_proj, Wproj_t, Cn, Cn);

    gemm128<1><<<dim3(NQKV / 128, Mn / 128), 256, 0, stream>>>(
        xb, Wqkv_t, b_attn, nullptr, Qb, Kb, Vt, Mn, NQKV, Cn);

    attn_kernel<<<dim3(8, BH), 256, 0, stream>>>(Qb, Kb, Vt, Yb);

    gemm128<0><<<dim3(Cn / 128, Mn / 128), 256, 0, stream>>>(
        Yb, Wproj_t, b_proj, out, nullptr, nullptr, nullptr, Mn, Cn, Cn);
}